// Round 1
// baseline (485.400 us; speedup 1.0000x reference)
//
#include <hip/hip_runtime.h>
#include <hip/hip_bf16.h>

typedef __attribute__((ext_vector_type(8))) short bf16x8;
typedef __attribute__((ext_vector_type(4))) float f32x4;

// fp32 -> bf16 round-to-nearest-even (inputs are finite randn; no NaN path needed)
static __device__ __forceinline__ short f2bf(float f) {
    union { float f; unsigned u; } v; v.f = f;
    unsigned r = v.u + 0x7FFFu + ((v.u >> 16) & 1u);
    return (short)(r >> 16);
}

// out[n,f] = ci[n] * sum_{e: dst[e]=n} (feat[e,:] @ W[f,:]) * ci[src[e]] * mask[e]
// Fold ci[dst] into the per-edge scalar so one atomic pass produces the final output.
__global__ __launch_bounds__(256, 4)
void gcn_fused_kernel(const float* __restrict__ feat,  // [E,64]
                      const float* __restrict__ ci,    // [N]
                      const float* __restrict__ W,     // [64,64] row-major [f][d]
                      const float* __restrict__ mask,  // [E]
                      const int* __restrict__ src,
                      const int* __restrict__ dst,
                      float* __restrict__ out,         // [N,64], pre-zeroed
                      int E, int nTiles)
{
    const int lane = threadIdx.x & 63;
    const int wave = threadIdx.x >> 6;
    const int r16  = lane & 15;   // A-row / B-col / C-col within 16
    const int q    = lane >> 4;   // quad: k-block selector

    // ---- B fragments: B[k][f] = W[f][k]; lane holds f = t*16 + r16, k = s*32 + q*8 + j.
    // Kept in registers for the whole kernel (64 bf16 = 32 VGPRs).
    bf16x8 bfrag[4][2];
#pragma unroll
    for (int t = 0; t < 4; ++t) {
        const float* wrow = W + (t * 16 + r16) * 64;
#pragma unroll
        for (int s = 0; s < 2; ++s) {
            const float4 w0 = *(const float4*)(wrow + s * 32 + q * 8);
            const float4 w1 = *(const float4*)(wrow + s * 32 + q * 8 + 4);
            bf16x8 b;
            b[0] = f2bf(w0.x); b[1] = f2bf(w0.y); b[2] = f2bf(w0.z); b[3] = f2bf(w0.w);
            b[4] = f2bf(w1.x); b[5] = f2bf(w1.y); b[6] = f2bf(w1.z); b[7] = f2bf(w1.w);
            bfrag[t][s] = b;
        }
    }

    for (int g = blockIdx.x; g < nTiles; g += gridDim.x) {
        const int e0 = g * 64 + wave * 16;   // this wave's 16 edges

        // ---- per-edge scalar s[e] and dst base, computed by lanes 0..15 only
        float sv = 0.0f;
        int dbase = 0;
        if (lane < 16) {
            const int eM = e0 + lane;
            if (eM < E) {
                const int is = src[eM];
                const int id = dst[eM];
                sv = ci[is] * mask[eM] * ci[id];
                dbase = id * 64;
            }
        }

        // ---- A fragments straight from global in MFMA layout:
        // lane holds feat[e0 + r16][k = s*32 + q*8 + j]
        int eA = e0 + r16;
        if (eA >= E) eA = E - 1;               // clamp (tail contributes 0 via sv)
        const float* arow = feat + (size_t)eA * 64 + q * 8;
        bf16x8 afrag[2];
#pragma unroll
        for (int s = 0; s < 2; ++s) {
            const float4 a0 = *(const float4*)(arow + s * 32);
            const float4 a1 = *(const float4*)(arow + s * 32 + 4);
            bf16x8 a;
            a[0] = f2bf(a0.x); a[1] = f2bf(a0.y); a[2] = f2bf(a0.z); a[3] = f2bf(a0.w);
            a[4] = f2bf(a1.x); a[5] = f2bf(a1.y); a[6] = f2bf(a1.z); a[7] = f2bf(a1.w);
            afrag[s] = a;
        }

        // ---- r-tile: 16 edges x 64 f  (4 f-tiles x 2 k-steps)
        f32x4 acc[4];
#pragma unroll
        for (int t = 0; t < 4; ++t) {
            f32x4 c = {0.f, 0.f, 0.f, 0.f};
            c = __builtin_amdgcn_mfma_f32_16x16x32_bf16(afrag[0], bfrag[t][0], c, 0, 0, 0);
            c = __builtin_amdgcn_mfma_f32_16x16x32_bf16(afrag[1], bfrag[t][1], c, 0, 0, 0);
            acc[t] = c;
        }

        // ---- scatter: C layout row = q*4 + reg (edge), col = r16 (f within tile)
#pragma unroll
        for (int r = 0; r < 4; ++r) {
            const int sl = q * 4 + r;                  // lane holding this edge's meta
            const float s_r = __shfl(sv, sl, 64);
            const int   b_r = __shfl(dbase, sl, 64);
#pragma unroll
            for (int t = 0; t < 4; ++t) {
                const float v = acc[t][r] * s_r;
                unsafeAtomicAdd(out + b_r + t * 16 + r16, v);
            }
        }
    }
}

extern "C" void kernel_launch(void* const* d_in, const int* in_sizes, int n_in,
                              void* d_out, int out_size, void* d_ws, size_t ws_size,
                              hipStream_t stream) {
    const float* feat = (const float*)d_in[0];
    const float* ci   = (const float*)d_in[1];
    const float* W    = (const float*)d_in[2];
    const float* mask = (const float*)d_in[3];
    const int*   src  = (const int*)d_in[4];
    const int*   dst  = (const int*)d_in[5];
    float* out = (float*)d_out;

    const int E = in_sizes[0] / 64;
    const int nTiles = (E + 63) / 64;

    hipMemsetAsync(d_out, 0, (size_t)out_size * sizeof(float), stream);

    int grid = 1024;
    if (nTiles < grid) grid = nTiles;
    gcn_fused_kernel<<<dim3(grid), dim3(256), 0, stream>>>(
        feat, ci, W, mask, src, dst, out, E, nTiles);
}